// Round 1
// baseline (1241.309 us; speedup 1.0000x reference)
//
#include <hip/hip_runtime.h>
#include <hip/hip_bf16.h>
#include <stdint.h>

#define B_   64
#define C_   3
#define J_   25
#define T_   256
#define CO_  64
#define N_   (B_*J_*T_)     // 409600 locations, loc = (b*J_+j)*T_ + t
#define SIGD 84             // 4 + 16 + 64

using bf16 = __hip_bfloat16;

// ---------------------------------------------------------------------------
// depth-3 signature of a 3-increment path in 4 dims.
// S layout: [S1(4) | S2(16, i*4+j) | S3(64, i*16+j*4+k)]
// ---------------------------------------------------------------------------
__device__ __forceinline__ void sig3(const float v0[4], const float v1[4],
                                     const float v2[4], float* __restrict__ S) {
    float* S1 = S;
    float* S2 = S + 4;
    float* S3 = S + 20;
    #pragma unroll
    for (int i = 0; i < 4; i++) S1[i] = v0[i];
    #pragma unroll
    for (int i = 0; i < 4; i++)
        #pragma unroll
        for (int j = 0; j < 4; j++) S2[i*4+j] = 0.5f * v0[i] * v0[j];
    #pragma unroll
    for (int i = 0; i < 4; i++)
        #pragma unroll
        for (int j = 0; j < 4; j++)
            #pragma unroll
            for (int k = 0; k < 4; k++)
                S3[i*16+j*4+k] = S2[i*4+j] * v0[k] * (1.f/3.f);

    const float* vs[2] = { v1, v2 };
    #pragma unroll
    for (int s = 0; s < 2; s++) {
        const float* v = vs[s];
        float B2[16], v3[4];
        #pragma unroll
        for (int k = 0; k < 4; k++) v3[k] = v[k] * (1.f/3.f);
        #pragma unroll
        for (int i = 0; i < 4; i++)
            #pragma unroll
            for (int j = 0; j < 4; j++) B2[i*4+j] = 0.5f * v[i] * v[j];
        // S3 += B3 + S1 (x) B2 + S2 (x) B1   (uses OLD S1,S2 — updated after)
        #pragma unroll
        for (int i = 0; i < 4; i++)
            #pragma unroll
            for (int j = 0; j < 4; j++)
                #pragma unroll
                for (int k = 0; k < 4; k++)
                    S3[i*16+j*4+k] += B2[i*4+j]*v3[k] + S1[i]*B2[j*4+k] + S2[i*4+j]*v[k];
        #pragma unroll
        for (int i = 0; i < 4; i++)
            #pragma unroll
            for (int j = 0; j < 4; j++) S2[i*4+j] += B2[i*4+j] + S1[i]*v[j];
        #pragma unroll
        for (int i = 0; i < 4; i++) S1[i] += v[i];
    }
}

// ---------------------------------------------------------------------------
// K0: fold signet weights through ps_w:
//   M1t[o][m] = sum_i sp_W[m][i] * ps_w[o][i]         (spatial half)
//   M2t[o][m] = sum_i tp_W[m][i] * ps_w[o][64+i]      (temporal half)
//   cb[o]     = ps_b[o] + sum_i ps_w[o][i]*sp_b[i] + ps_w[o][64+i]*tp_b[i]
// ---------------------------------------------------------------------------
__global__ void k_prep(const float* __restrict__ sp_W, const float* __restrict__ sp_b,
                       const float* __restrict__ tp_W, const float* __restrict__ tp_b,
                       const float* __restrict__ ps_w, const float* __restrict__ ps_b,
                       float* __restrict__ M1t, float* __restrict__ M2t,
                       float* __restrict__ cb) {
    int o = blockIdx.x;
    int m = threadIdx.x;
    if (m < SIGD) {
        float a1 = 0.f, a2 = 0.f;
        for (int i = 0; i < 64; i++) {
            a1 += sp_W[m*64+i] * ps_w[o*128+i];
            a2 += tp_W[m*64+i] * ps_w[o*128+64+i];
        }
        M1t[o*SIGD+m] = a1;
        M2t[o*SIGD+m] = a2;
    } else if (m == SIGD) {
        float a = ps_b[o];
        for (int i = 0; i < 64; i++)
            a += ps_w[o*128+i]*sp_b[i] + ps_w[o*128+64+i]*tp_b[i];
        cb[o] = a;
    }
}

// ---------------------------------------------------------------------------
// K1: conv1x3 over T (zero pad) + bias + relu -> z_conv[o][loc]  (bf16)
// block = 256 threads over t; grid = B*CO*J
// ---------------------------------------------------------------------------
__global__ __launch_bounds__(256) void k_conv(const float* __restrict__ x,
                                              const float* __restrict__ w,
                                              const float* __restrict__ cbias,
                                              bf16* __restrict__ z_conv) {
    int id = blockIdx.x;
    int j = id % J_;
    int o = (id / J_) % CO_;
    int b = id / (J_ * CO_);
    int t = threadIdx.x;
    float acc = cbias[o];
    #pragma unroll
    for (int c = 0; c < 3; c++) {
        const float* xr = x + ((b*3+c)*J_ + j)*T_;
        float xm = (t > 0)      ? xr[t-1] : 0.f;
        float x0 = xr[t];
        float xp = (t < T_-1)   ? xr[t+1] : 0.f;
        const float* wr = w + (o*3+c)*3;
        acc += wr[0]*xm + wr[1]*x0 + wr[2]*xp;
    }
    acc = fmaxf(acc, 0.f);
    z_conv[(size_t)o*N_ + (size_t)(b*J_+j)*T_ + t] = __float2bfloat16(acc);
}

// ---------------------------------------------------------------------------
// K2: spatial + temporal signatures, folded matvec through M1t/M2t, relu
//     -> z_ps[o][loc]  (bf16).  block = 256 over t; grid = B*J
// ---------------------------------------------------------------------------
__global__ __launch_bounds__(256) void k_sig(const float* __restrict__ x,
                                             const int* __restrict__ nbr,
                                             const float* __restrict__ M1t,
                                             const float* __restrict__ M2t,
                                             const float* __restrict__ cb,
                                             bf16* __restrict__ z_ps) {
    int bj = blockIdx.x;
    int b = bj / J_;
    int j = bj % J_;
    int t = threadIdx.x;
    int loc = bj * T_ + t;

    // ---- spatial path: points (time_k, x[b, :, nbr[j][k], t]) ----
    int n0 = nbr[j*3+0], n1 = nbr[j*3+1], n2 = nbr[j*3+2];
    float p0[4], p1[4], p2[4];
    p0[0] = 0.f; p1[0] = 0.5f; p2[0] = 1.0f;
    #pragma unroll
    for (int c = 0; c < 3; c++) {
        const float* xb = x + (size_t)((b*3+c)*J_)*T_ + t;
        p0[c+1] = xb[n0*T_];
        p1[c+1] = xb[n1*T_];
        p2[c+1] = xb[n2*T_];
    }
    float v0[4], v1[4], v2[4];
    #pragma unroll
    for (int d = 0; d < 4; d++) { v0[d]=p0[d]; v1[d]=p1[d]-p0[d]; v2[d]=p2[d]-p1[d]; }
    float sps[SIGD];
    sig3(v0, v1, v2, sps);

    // ---- temporal path: points (time_k, x[b, :, j, clamp(t-1+k)]) (edge pad) ----
    int tm = (t > 0)    ? t-1 : 0;
    int tp = (t < T_-1) ? t+1 : T_-1;
    p0[0] = 0.f; p1[0] = 0.5f; p2[0] = 1.0f;
    #pragma unroll
    for (int c = 0; c < 3; c++) {
        const float* xr = x + (size_t)((b*3+c)*J_ + j)*T_;
        p0[c+1] = xr[tm];
        p1[c+1] = xr[t];
        p2[c+1] = xr[tp];
    }
    #pragma unroll
    for (int d = 0; d < 4; d++) { v0[d]=p0[d]; v1[d]=p1[d]-p0[d]; v2[d]=p2[d]-p1[d]; }
    float tps[SIGD];
    sig3(v0, v1, v2, tps);

    // ---- folded (sig -> signet -> ps) matvec, relu, store ----
    for (int o = 0; o < CO_; o++) {
        const float* m1 = M1t + o*SIGD;
        const float* m2 = M2t + o*SIGD;
        float acc = cb[o];
        #pragma unroll
        for (int m = 0; m < SIGD; m++) acc += sps[m]*m1[m];
        #pragma unroll
        for (int m = 0; m < SIGD; m++) acc += tps[m]*m2[m];
        z_ps[(size_t)o*N_ + loc] = __float2bfloat16(fmaxf(acc, 0.f));
    }
}

// ---------------------------------------------------------------------------
// per-channel sum / sumsq over N_ elements of a [64][N_] bf16 tensor.
// grid = (100, 64); block = 256; each block covers 4096 contiguous elems.
// ---------------------------------------------------------------------------
__global__ __launch_bounds__(256) void k_stats(const bf16* __restrict__ z,
                                               float* __restrict__ sum,
                                               float* __restrict__ ssq) {
    int ch = blockIdx.y;
    const uint4* p = (const uint4*)(z + (size_t)ch*N_ + (size_t)blockIdx.x*4096);
    float s = 0.f, q = 0.f;
    #pragma unroll
    for (int r = 0; r < 2; r++) {
        uint4 v = p[r*256 + threadIdx.x];
        uint32_t u[4] = { v.x, v.y, v.z, v.w };
        #pragma unroll
        for (int k = 0; k < 4; k++) {
            float f0 = __uint_as_float(u[k] << 16);
            float f1 = __uint_as_float(u[k] & 0xffff0000u);
            s += f0 + f1;
            q += f0*f0 + f1*f1;
        }
    }
    #pragma unroll
    for (int off = 32; off > 0; off >>= 1) {
        s += __shfl_down(s, off);
        q += __shfl_down(q, off);
    }
    __shared__ float lds[8];
    int wave = threadIdx.x >> 6, lane = threadIdx.x & 63;
    if (lane == 0) { lds[wave*2] = s; lds[wave*2+1] = q; }
    __syncthreads();
    if (threadIdx.x == 0) {
        s = lds[0] + lds[2] + lds[4] + lds[6];
        q = lds[1] + lds[3] + lds[5] + lds[7];
        atomicAdd(sum + ch, s);
        atomicAdd(ssq + ch, q);
    }
}

// ---------------------------------------------------------------------------
// K3: finalize conv/ps BN stats and fold both BNs into fu_w:
//   w1s[o][i] = fu_w[o][i]   * a_conv[i],  w2s[o][i] = fu_w[o][64+i] * a_ps[i]
//   fb2[o]    = fu_b[o] + sum_i fu_w[o][i]*d_conv[i] + fu_w[o][64+i]*d_ps[i]
// ---------------------------------------------------------------------------
__global__ void k_fin1(const float* __restrict__ sum_c, const float* __restrict__ ssq_c,
                       const float* __restrict__ sum_p, const float* __restrict__ ssq_p,
                       const float* __restrict__ raw_g, const float* __restrict__ raw_b,
                       const float* __restrict__ ps_g,  const float* __restrict__ ps_bt,
                       const float* __restrict__ fu_w,  const float* __restrict__ fu_b,
                       float* __restrict__ w1s, float* __restrict__ w2s,
                       float* __restrict__ fb2) {
    __shared__ float ac[64], dc[64], ap[64], dp[64];
    int i = threadIdx.x;
    const float inv = 1.f / (float)N_;
    float mc = sum_c[i]*inv, vc = ssq_c[i]*inv - mc*mc;
    float a1 = rsqrtf(vc + 1e-5f) * raw_g[i];
    ac[i] = a1; dc[i] = raw_b[i] - mc*a1;
    float mp = sum_p[i]*inv, vp = ssq_p[i]*inv - mp*mp;
    float a2 = rsqrtf(vp + 1e-5f) * ps_g[i];
    ap[i] = a2; dp[i] = ps_bt[i] - mp*a2;
    __syncthreads();
    int o = i;
    float fb = fu_b[o];
    for (int k = 0; k < 64; k++) {
        float wc = fu_w[o*128 + k];
        float wp = fu_w[o*128 + 64 + k];
        fb += wc*dc[k] + wp*dp[k];
        w1s[o*64 + k] = wc * ac[k];
        w2s[o*64 + k] = wp * ap[k];
    }
    fb2[o] = fb;
}

// ---------------------------------------------------------------------------
// K4: fused-BN fu matvec + relu -> z_fu[o][loc]
// ---------------------------------------------------------------------------
__global__ __launch_bounds__(256) void k_fu(const bf16* __restrict__ z_conv,
                                            const bf16* __restrict__ z_ps,
                                            const float* __restrict__ w1s,
                                            const float* __restrict__ w2s,
                                            const float* __restrict__ fb2,
                                            bf16* __restrict__ z_fu) {
    int loc = blockIdx.x*256 + threadIdx.x;
    float zc[64], zp[64];
    #pragma unroll
    for (int i = 0; i < 64; i++) {
        zc[i] = __bfloat162float(z_conv[(size_t)i*N_ + loc]);
        zp[i] = __bfloat162float(z_ps[(size_t)i*N_ + loc]);
    }
    for (int o = 0; o < 64; o++) {
        const float* wa = w1s + o*64;
        const float* wb = w2s + o*64;
        float acc = fb2[o];
        #pragma unroll
        for (int i = 0; i < 64; i++) acc += wa[i]*zc[i];
        #pragma unroll
        for (int i = 0; i < 64; i++) acc += wb[i]*zp[i];
        z_fu[(size_t)o*N_ + loc] = __float2bfloat16(fmaxf(acc, 0.f));
    }
}

// ---------------------------------------------------------------------------
// K5: finalize fu BN stats
// ---------------------------------------------------------------------------
__global__ void k_fin2(const float* __restrict__ sum_f, const float* __restrict__ ssq_f,
                       const float* __restrict__ fu_g,
                       float* __restrict__ mf, float* __restrict__ rfg) {
    int o = threadIdx.x;
    const float inv = 1.f / (float)N_;
    float m = sum_f[o]*inv, v = ssq_f[o]*inv - m*m;
    mf[o] = m;
    rfg[o] = rsqrtf(v + 1e-5f) * fu_g[o];
}

// ---------------------------------------------------------------------------
// K6: apply fu BN, write f32 output [b][o][j][t]
// ---------------------------------------------------------------------------
__global__ __launch_bounds__(256) void k_out(const bf16* __restrict__ z_fu,
                                             const float* __restrict__ mf,
                                             const float* __restrict__ rfg,
                                             const float* __restrict__ fu_beta,
                                             float* __restrict__ out) {
    int idx  = blockIdx.x*256 + threadIdx.x;
    int t    = idx & (T_-1);
    int rest = idx >> 8;            // (b*64 + o)*25 + j
    int j    = rest % J_;
    int bo   = rest / J_;
    int o    = bo & 63;
    int b    = bo >> 6;
    int loc  = (b*J_ + j)*T_ + t;
    float v = __bfloat162float(z_fu[(size_t)o*N_ + loc]);
    out[idx] = (v - mf[o]) * rfg[o] + fu_beta[o];
}

// ---------------------------------------------------------------------------
extern "C" void kernel_launch(void* const* d_in, const int* in_sizes, int n_in,
                              void* d_out, int out_size, void* d_ws, size_t ws_size,
                              hipStream_t stream) {
    const float* x         = (const float*)d_in[0];
    const float* conv_w    = (const float*)d_in[1];
    const float* conv_b    = (const float*)d_in[2];
    const float* raw_gamma = (const float*)d_in[3];
    const float* raw_beta  = (const float*)d_in[4];
    const float* sp_W      = (const float*)d_in[5];
    const float* sp_b      = (const float*)d_in[6];
    const float* tp_W      = (const float*)d_in[7];
    const float* tp_b      = (const float*)d_in[8];
    const float* ps_w      = (const float*)d_in[9];
    const float* ps_b      = (const float*)d_in[10];
    const float* ps_gamma  = (const float*)d_in[11];
    const float* ps_beta   = (const float*)d_in[12];
    const float* fu_w      = (const float*)d_in[13];
    const float* fu_b      = (const float*)d_in[14];
    const float* fu_gamma  = (const float*)d_in[15];
    const float* fu_beta   = (const float*)d_in[16];
    const int*   neighbors = (const int*)d_in[17];

    char* ws = (char*)d_ws;
    const size_t ZBYTES = (size_t)CO_ * N_ * sizeof(bf16);   // 52,428,800 B
    bf16*  z_conv = (bf16*)(ws);
    bf16*  z_ps   = (bf16*)(ws + ZBYTES);
    bf16*  z_fu   = (bf16*)(ws + 2*ZBYTES);
    float* f32s   = (float*)(ws + 3*ZBYTES);
    float* M1t  = f32s;               // 64*84
    float* M2t  = M1t + 64*SIGD;      // 64*84
    float* cb   = M2t + 64*SIGD;      // 64
    float* w1s  = cb  + 64;           // 64*64
    float* w2s  = w1s + 64*64;        // 64*64
    float* fb2  = w2s + 64*64;        // 64
    float* mf   = fb2 + 64;           // 64
    float* rfg  = mf  + 64;           // 64
    float* stats = rfg + 64;          // 6*64 accumulators (must be zeroed)
    float* sum_c = stats;       float* ssq_c = stats + 64;
    float* sum_p = stats + 128; float* ssq_p = stats + 192;
    float* sum_f = stats + 256; float* ssq_f = stats + 320;

    hipMemsetAsync(stats, 0, 6*64*sizeof(float), stream);

    k_prep<<<64, 96, 0, stream>>>(sp_W, sp_b, tp_W, tp_b, ps_w, ps_b, M1t, M2t, cb);
    k_conv<<<B_*CO_*J_, 256, 0, stream>>>(x, conv_w, conv_b, z_conv);
    k_sig<<<B_*J_, 256, 0, stream>>>(x, neighbors, M1t, M2t, cb, z_ps);
    k_stats<<<dim3(100, 64), 256, 0, stream>>>(z_conv, sum_c, ssq_c);
    k_stats<<<dim3(100, 64), 256, 0, stream>>>(z_ps, sum_p, ssq_p);
    k_fin1<<<1, 64, 0, stream>>>(sum_c, ssq_c, sum_p, ssq_p,
                                 raw_gamma, raw_beta, ps_gamma, ps_beta,
                                 fu_w, fu_b, w1s, w2s, fb2);
    k_fu<<<B_*J_, 256, 0, stream>>>(z_conv, z_ps, w1s, w2s, fb2, z_fu);
    k_stats<<<dim3(100, 64), 256, 0, stream>>>(z_fu, sum_f, ssq_f);
    k_fin2<<<1, 64, 0, stream>>>(sum_f, ssq_f, fu_gamma, mf, rfg);
    k_out<<<(B_*CO_*J_*T_)/256, 256, 0, stream>>>(z_fu, mf, rfg, fu_beta, (float*)d_out);
}

// Round 4
// 459.339 us; speedup vs baseline: 2.7024x; 2.7024x over previous
//
#include <hip/hip_runtime.h>
#include <hip/hip_bf16.h>
#include <stdint.h>

#define B_   64
#define C_   3
#define J_   25
#define T_   256
#define CO_  64
#define N_   (B_*J_*T_)     // 409600 locations, loc = (b*J_+j)*T_ + t
#define SIGD 84
#define FSTR 177            // feats LDS stride (f32) — odd*32+17: 2-way banks only
#define ZSTR 133            // zt LDS stride (f32)    — odd: 2-way banks only

__device__ __forceinline__ unsigned short f2b(float f) {
    unsigned int u = __float_as_uint(f);
    u += 0x7fffu + ((u >> 16) & 1u);          // round-to-nearest-even
    return (unsigned short)(u >> 16);
}
__device__ __forceinline__ float b2f(unsigned int bits_lo16) {
    return __uint_as_float(bits_lo16 << 16);
}
__device__ __forceinline__ unsigned int pack2(float a, float b) {
    return (unsigned int)f2b(a) | ((unsigned int)f2b(b) << 16);
}

// ---------------------------------------------------------------------------
// depth-3 signature of a 3-increment path in 4 dims (verified round 1).
// S layout: [S1(4) | S2(16, i*4+j) | S3(64, i*16+j*4+k)]
// ---------------------------------------------------------------------------
__device__ __forceinline__ void sig3(const float v0[4], const float v1[4],
                                     const float v2[4], float* __restrict__ S) {
    float* S1 = S;
    float* S2 = S + 4;
    float* S3 = S + 20;
    #pragma unroll
    for (int i = 0; i < 4; i++) S1[i] = v0[i];
    #pragma unroll
    for (int i = 0; i < 4; i++)
        #pragma unroll
        for (int j = 0; j < 4; j++) S2[i*4+j] = 0.5f * v0[i] * v0[j];
    #pragma unroll
    for (int i = 0; i < 4; i++)
        #pragma unroll
        for (int j = 0; j < 4; j++)
            #pragma unroll
            for (int k = 0; k < 4; k++)
                S3[i*16+j*4+k] = S2[i*4+j] * v0[k] * (1.f/3.f);

    #pragma unroll
    for (int s = 0; s < 2; s++) {
        const float* v = (s == 0) ? v1 : v2;
        float B2[16], v3[4];
        #pragma unroll
        for (int k = 0; k < 4; k++) v3[k] = v[k] * (1.f/3.f);
        #pragma unroll
        for (int i = 0; i < 4; i++)
            #pragma unroll
            for (int j = 0; j < 4; j++) B2[i*4+j] = 0.5f * v[i] * v[j];
        #pragma unroll
        for (int i = 0; i < 4; i++)
            #pragma unroll
            for (int j = 0; j < 4; j++)
                #pragma unroll
                for (int k = 0; k < 4; k++)
                    S3[i*16+j*4+k] += B2[i*4+j]*v3[k] + S1[i]*B2[j*4+k] + S2[i*4+j]*v[k];
        #pragma unroll
        for (int i = 0; i < 4; i++)
            #pragma unroll
            for (int j = 0; j < 4; j++) S2[i*4+j] += B2[i*4+j] + S1[i]*v[j];
        #pragma unroll
        for (int i = 0; i < 4; i++) S1[i] += v[i];
    }
}

// ---------------------------------------------------------------------------
// K0: fold signet weights through ps_w into f32 wsig_t[168][64] (k-major):
//   k<84      : wsig_t[k][o]    = sum_i sp_W[k][i]  * ps_w[o][i]
//   84<=k<168 : wsig_t[k][o]    = sum_i tp_W[k-84][i]*ps_w[o][64+i]
// cb[o] = folded bias (f32).  grid=169 (k; 168=bias), block=64 (o).
// ---------------------------------------------------------------------------
__global__ void k_prep(const float* __restrict__ sp_W, const float* __restrict__ sp_b,
                       const float* __restrict__ tp_W, const float* __restrict__ tp_b,
                       const float* __restrict__ ps_w, const float* __restrict__ ps_b,
                       float* __restrict__ wsig_t, float* __restrict__ cb) {
    int k = blockIdx.x;
    int o = threadIdx.x;
    if (k < SIGD) {
        float v = 0.f;
        for (int i = 0; i < 64; i++) v += sp_W[k*64+i] * ps_w[o*128+i];
        wsig_t[k*64 + o] = v;
    } else if (k < 2*SIGD) {
        int m = k - SIGD;
        float v = 0.f;
        for (int i = 0; i < 64; i++) v += tp_W[m*64+i] * ps_w[o*128+64+i];
        wsig_t[k*64 + o] = v;
    } else {
        float a = ps_b[o];
        for (int i = 0; i < 64; i++)
            a += ps_w[o*128+i]*sp_b[i] + ps_w[o*128+64+i]*tp_b[i];
        cb[o] = a;
    }
}

// ---------------------------------------------------------------------------
// K1: fused conv1x3 + signatures + scalar f32 folded matvec.
// Block 256 thr, 64 locs. Phase A: thr 0..127 sig gen (2 paths/loc) -> LDS
// f32 feats[64][FSTR] (spatial cols 0..83, temporal 84..167); thr 128..255
// conv -> zcat ch 0..63. Phase B: 4 waves x 64 locs, wave og computes
// 16 outputs (o=og*16..+16) per loc from LDS feats + wave-uniform weights.
// Grid: 1600 (b,j) x 4 quarters.
// ---------------------------------------------------------------------------
__global__ __launch_bounds__(256) void k_sig(const float* __restrict__ x,
                                             const int* __restrict__ nbr,
                                             const float* __restrict__ wsig_t,
                                             const float* __restrict__ cb,
                                             const float* __restrict__ conv_w,
                                             const float* __restrict__ conv_b,
                                             unsigned short* __restrict__ zcat) {
    __shared__ float feats[64*FSTR];   // 45312 B

    const int i       = threadIdx.x;
    const int quarter = blockIdx.x & 3;
    const int bj      = blockIdx.x >> 2;
    const int b       = bj / J_, j = bj % J_;
    const int loc_base = bj*T_ + quarter*64;

    if (i < 128) {
        // ---- signature features (one path per thread) -> LDS f32 ----
        const int lt   = i >> 1;
        const int path = i & 1;
        const int t    = quarter*64 + lt;
        float p0[4], p1[4], p2[4];
        p0[0] = 0.f; p1[0] = 0.5f; p2[0] = 1.0f;
        if (path == 0) {
            int n0 = nbr[j*3+0], n1 = nbr[j*3+1], n2 = nbr[j*3+2];
            #pragma unroll
            for (int c = 0; c < 3; c++) {
                const float* xc = x + ((size_t)(b*3+c)*J_)*T_ + t;
                p0[c+1] = xc[n0*T_];
                p1[c+1] = xc[n1*T_];
                p2[c+1] = xc[n2*T_];
            }
        } else {
            int tm = (t > 0)    ? t-1 : 0;
            int tp = (t < T_-1) ? t+1 : T_-1;
            #pragma unroll
            for (int c = 0; c < 3; c++) {
                const float* xr = x + ((size_t)(b*3+c)*J_ + j)*T_;
                p0[c+1] = xr[tm];
                p1[c+1] = xr[t];
                p2[c+1] = xr[tp];
            }
        }
        float v0[4], v1[4], v2[4];
        #pragma unroll
        for (int d = 0; d < 4; d++) { v0[d]=p0[d]; v1[d]=p1[d]-p0[d]; v2[d]=p2[d]-p1[d]; }
        float S[SIGD];
        sig3(v0, v1, v2, S);
        float* frow = feats + lt*FSTR + path*SIGD;
        #pragma unroll
        for (int m = 0; m < SIGD; m++) frow[m] = S[m];
    } else {
        // ---- conv1x3 (zero pad), each thread: 1 loc x 32 channels ----
        const int ci  = i - 128;
        const int lt  = ci >> 1;
        const int chh = ci & 1;
        const int t   = quarter*64 + lt;
        const int loc = loc_base + lt;
        float xm[3], x0[3], xp[3];
        #pragma unroll
        for (int c = 0; c < 3; c++) {
            const float* xr = x + ((size_t)(b*3+c)*J_ + j)*T_;
            xm[c] = (t > 0)     ? xr[t-1] : 0.f;
            x0[c] = xr[t];
            xp[c] = (t < T_-1)  ? xr[t+1] : 0.f;
        }
        unsigned int packed[16];
        #pragma unroll
        for (int oo2 = 0; oo2 < 16; oo2++) {
            float r[2];
            #pragma unroll
            for (int e = 0; e < 2; e++) {
                int o = chh*32 + oo2*2 + e;
                float acc = conv_b[o];
                #pragma unroll
                for (int c = 0; c < 3; c++) {
                    const float* wr = conv_w + (o*3+c)*3;
                    acc += wr[0]*xm[c] + wr[1]*x0[c] + wr[2]*xp[c];
                }
                r[e] = fmaxf(acc, 0.f);
            }
            packed[oo2] = pack2(r[0], r[1]);
        }
        uint4* dst = (uint4*)(zcat + (size_t)loc*128 + chh*32);
        #pragma unroll
        for (int k = 0; k < 4; k++)
            dst[k] = make_uint4(packed[k*4+0], packed[k*4+1], packed[k*4+2], packed[k*4+3]);
    }
    __syncthreads();

    // ---- scalar matvec: z_ps[loc][o] = relu(sum_k w[k][o]*f[loc][k]+cb) ----
    const int og = __builtin_amdgcn_readfirstlane(i >> 6);   // wave-uniform o-tile
    const int lt = i & 63;
    const int loc = loc_base + lt;
    const float* wt  = wsig_t + og*16;       // + k*64
    const float* cbp = cb + og*16;
    float acc[16];
    #pragma unroll
    for (int oo = 0; oo < 16; oo++) acc[oo] = cbp[oo];
    const float* frow = feats + lt*FSTR;
    #pragma unroll 4
    for (int k = 0; k < 2*SIGD; k++) {
        float f = frow[k];
        const float* w = wt + k*64;
        #pragma unroll
        for (int oo = 0; oo < 16; oo++) acc[oo] = fmaf(f, w[oo], acc[oo]);
    }
    unsigned int pk[8];
    #pragma unroll
    for (int p = 0; p < 8; p++)
        pk[p] = pack2(fmaxf(acc[2*p],0.f), fmaxf(acc[2*p+1],0.f));
    uint4* dst = (uint4*)(zcat + (size_t)loc*128 + 64 + og*16);
    dst[0] = make_uint4(pk[0], pk[1], pk[2], pk[3]);
    dst[1] = make_uint4(pk[4], pk[5], pk[6], pk[7]);
}

// ---------------------------------------------------------------------------
// per-channel sum/ssq over [N_][NCH] bf16. grid=256 blocks, 1600 locs each.
// ---------------------------------------------------------------------------
template<int NCH>
__global__ __launch_bounds__(256) void k_stats(const unsigned short* __restrict__ z,
                                               float* __restrict__ sum,
                                               float* __restrict__ ssq) {
    constexpr int G  = NCH/8;       // ch-groups of 8
    constexpr int LP = 256/G;       // locs per pass
    const int i = threadIdx.x;
    const int g = i % G;
    const int lr = i / G;
    const int base = blockIdx.x * 1600;
    float s[8], qq[8];
    #pragma unroll
    for (int k = 0; k < 8; k++) { s[k] = 0.f; qq[k] = 0.f; }
    for (int l = lr; l < 1600; l += LP) {
        const uint4 v = *(const uint4*)(z + (size_t)(base + l)*NCH + g*8);
        unsigned int u[4] = { v.x, v.y, v.z, v.w };
        #pragma unroll
        for (int k = 0; k < 4; k++) {
            float f0 = b2f(u[k] & 0xffffu);
            float f1 = __uint_as_float(u[k] & 0xffff0000u);
            s[2*k]   += f0;  qq[2*k]   += f0*f0;
            s[2*k+1] += f1;  qq[2*k+1] += f1*f1;
        }
    }
    const int lane = i & 63, wv = i >> 6;
    for (int off = 32; off >= G; off >>= 1) {
        #pragma unroll
        for (int k = 0; k < 8; k++) {
            s[k]  += __shfl_down(s[k],  off);
            qq[k] += __shfl_down(qq[k], off);
        }
    }
    __shared__ float red[4][G][16];
    if (lane < G) {
        #pragma unroll
        for (int k = 0; k < 8; k++) { red[wv][lane][k] = s[k]; red[wv][lane][8+k] = qq[k]; }
    }
    __syncthreads();
    if (i < G*16) {
        int g2 = i >> 4, slot = i & 15;
        float v = red[0][g2][slot] + red[1][g2][slot] + red[2][g2][slot] + red[3][g2][slot];
        int ch = g2*8 + (slot & 7);
        atomicAdd((slot < 8 ? sum : ssq) + ch, v);
    }
}

// ---------------------------------------------------------------------------
// K3: finalize conv/ps BN; fold into f32 w12s_t[128][64] (k-major) + fb2.
// ---------------------------------------------------------------------------
__global__ void k_fin1(const float* __restrict__ sum_cp, const float* __restrict__ ssq_cp,
                       const float* __restrict__ raw_g, const float* __restrict__ raw_b,
                       const float* __restrict__ ps_g,  const float* __restrict__ ps_bt,
                       const float* __restrict__ fu_w,  const float* __restrict__ fu_b,
                       float* __restrict__ w12s_t, float* __restrict__ fb2) {
    __shared__ float a[128], d[128];
    int i = threadIdx.x;    // 64
    const float inv = 1.f / (float)N_;
    {
        float m = sum_cp[i]*inv, v = ssq_cp[i]*inv - m*m;
        float sc = rsqrtf(v + 1e-5f) * raw_g[i];
        a[i] = sc; d[i] = raw_b[i] - m*sc;
    }
    {
        float m = sum_cp[64+i]*inv, v = ssq_cp[64+i]*inv - m*m;
        float sc = rsqrtf(v + 1e-5f) * ps_g[i];
        a[64+i] = sc; d[64+i] = ps_bt[i] - m*sc;
    }
    __syncthreads();
    int o = i;
    float fb = fu_b[o];
    for (int k = 0; k < 128; k++) {
        float w = fu_w[o*128 + k];
        fb += w * d[k];
        w12s_t[k*64 + o] = w * a[k];
    }
    fb2[o] = fb;
}

// ---------------------------------------------------------------------------
// K4: fu scalar matvec: z_fu[loc][64] = relu(sum_k w12[k][o]*zcat[loc][k]+fb2)
// Block 256 thr, 64 locs (LDS f32 stage), 4 waves x 16 outputs. Grid 6400.
// ---------------------------------------------------------------------------
__global__ __launch_bounds__(256) void k_fu(const unsigned short* __restrict__ zcat,
                                            const float* __restrict__ w12s_t,
                                            const float* __restrict__ fb2,
                                            unsigned short* __restrict__ z_fu) {
    __shared__ float zt[64*ZSTR];   // 34048 B
    const int i = threadIdx.x;
    const int loc_base = blockIdx.x * 64;

    for (int c = i; c < 1024; c += 256) {
        int row = c >> 4, seg = c & 15;
        uint4 v = *(const uint4*)(zcat + (size_t)(loc_base + row)*128 + seg*8);
        float* drow = zt + row*ZSTR + seg*8;
        unsigned int u[4] = { v.x, v.y, v.z, v.w };
        #pragma unroll
        for (int e = 0; e < 4; e++) {
            drow[2*e]   = b2f(u[e] & 0xffffu);
            drow[2*e+1] = __uint_as_float(u[e] & 0xffff0000u);
        }
    }
    __syncthreads();

    const int og = __builtin_amdgcn_readfirstlane(i >> 6);
    const int lt = i & 63;
    const int loc = loc_base + lt;
    const float* wt  = w12s_t + og*16;   // + k*64
    const float* fbp = fb2 + og*16;
    float acc[16];
    #pragma unroll
    for (int oo = 0; oo < 16; oo++) acc[oo] = fbp[oo];
    const float* frow = zt + lt*ZSTR;
    #pragma unroll 4
    for (int k = 0; k < 128; k++) {
        float f = frow[k];
        const float* w = wt + k*64;
        #pragma unroll
        for (int oo = 0; oo < 16; oo++) acc[oo] = fmaf(f, w[oo], acc[oo]);
    }
    unsigned int pk[8];
    #pragma unroll
    for (int p = 0; p < 8; p++)
        pk[p] = pack2(fmaxf(acc[2*p],0.f), fmaxf(acc[2*p+1],0.f));
    uint4* dst = (uint4*)(z_fu + (size_t)loc*64 + og*16);
    dst[0] = make_uint4(pk[0], pk[1], pk[2], pk[3]);
    dst[1] = make_uint4(pk[4], pk[5], pk[6], pk[7]);
}

// ---------------------------------------------------------------------------
// K5: finalize fu BN stats
// ---------------------------------------------------------------------------
__global__ void k_fin2(const float* __restrict__ sum_f, const float* __restrict__ ssq_f,
                       const float* __restrict__ fu_g,
                       float* __restrict__ mf, float* __restrict__ rfg) {
    int o = threadIdx.x;
    const float inv = 1.f / (float)N_;
    float m = sum_f[o]*inv, v = ssq_f[o]*inv - m*m;
    mf[o] = m;
    rfg[o] = rsqrtf(v + 1e-5f) * fu_g[o];
}

// ---------------------------------------------------------------------------
// K6: apply fu BN, transpose [loc][64] -> out [b][o][j][t] f32 via LDS.
// grid = 1600 (b,j); block 256 (t).
// ---------------------------------------------------------------------------
__global__ __launch_bounds__(256) void k_out(const unsigned short* __restrict__ z_fu,
                                             const float* __restrict__ mf,
                                             const float* __restrict__ rfg,
                                             const float* __restrict__ fu_beta,
                                             float* __restrict__ out) {
    __shared__ __align__(16) unsigned short zt[256*66];    // stride 66 el
    const int i = threadIdx.x;
    const int bj = blockIdx.x;
    const int b = bj / J_, j = bj % J_;
    const int loc_base = bj * T_;

    for (int c = i; c < 2048; c += 256) {
        int row = c >> 3, k = c & 7;
        uint4 v = *(const uint4*)(z_fu + (size_t)(loc_base + row)*64 + k*8);
        unsigned int* dst = (unsigned int*)(zt + row*66 + k*8);
        dst[0] = v.x; dst[1] = v.y; dst[2] = v.z; dst[3] = v.w;
    }
    __syncthreads();

    const int t = i;
    const unsigned int* zrow = (const unsigned int*)zt + t*33;
    for (int o = 0; o < 64; o += 2) {
        unsigned int v = zrow[o >> 1];
        float f0 = b2f(v & 0xffffu);
        float f1 = __uint_as_float(v & 0xffff0000u);
        out[(((size_t)b*64 + o  )*J_ + j)*T_ + t] = (f0 - mf[o  ])*rfg[o  ] + fu_beta[o  ];
        out[(((size_t)b*64 + o+1)*J_ + j)*T_ + t] = (f1 - mf[o+1])*rfg[o+1] + fu_beta[o+1];
    }
}

// ---------------------------------------------------------------------------
extern "C" void kernel_launch(void* const* d_in, const int* in_sizes, int n_in,
                              void* d_out, int out_size, void* d_ws, size_t ws_size,
                              hipStream_t stream) {
    const float* x         = (const float*)d_in[0];
    const float* conv_w    = (const float*)d_in[1];
    const float* conv_b    = (const float*)d_in[2];
    const float* raw_gamma = (const float*)d_in[3];
    const float* raw_beta  = (const float*)d_in[4];
    const float* sp_W      = (const float*)d_in[5];
    const float* sp_b      = (const float*)d_in[6];
    const float* tp_W      = (const float*)d_in[7];
    const float* tp_b      = (const float*)d_in[8];
    const float* ps_w      = (const float*)d_in[9];
    const float* ps_b      = (const float*)d_in[10];
    const float* ps_gamma  = (const float*)d_in[11];
    const float* ps_beta   = (const float*)d_in[12];
    const float* fu_w      = (const float*)d_in[13];
    const float* fu_b      = (const float*)d_in[14];
    const float* fu_gamma  = (const float*)d_in[15];
    const float* fu_beta   = (const float*)d_in[16];
    const int*   neighbors = (const int*)d_in[17];

    char* ws = (char*)d_ws;
    unsigned short* zcat   = (unsigned short*)ws;                      // [N][128] bf16
    unsigned short* z_fu   = (unsigned short*)(ws + 104857600);        // [N][64] bf16
    size_t off = 157286400;
    float* wsig_t = (float*)(ws + off); off += 168*64*4;               // [168][64] f32
    float* w12s_t = (float*)(ws + off); off += 128*64*4;               // [128][64] f32
    float* f32s   = (float*)(ws + off);
    float* cb     = f32s;          // 64
    float* fb2    = f32s + 64;     // 64
    float* mf     = f32s + 128;    // 64
    float* rfg    = f32s + 192;    // 64
    float* sum_cp = f32s + 256;    // 128
    float* ssq_cp = f32s + 384;    // 128
    float* sum_f  = f32s + 512;    // 64
    float* ssq_f  = f32s + 576;    // 64

    hipMemsetAsync(sum_cp, 0, 384*sizeof(float), stream);

    k_prep<<<169, 64, 0, stream>>>(sp_W, sp_b, tp_W, tp_b, ps_w, ps_b, wsig_t, cb);
    k_sig<<<6400, 256, 0, stream>>>(x, neighbors, wsig_t, cb, conv_w, conv_b, zcat);
    k_stats<128><<<256, 256, 0, stream>>>(zcat, sum_cp, ssq_cp);
    k_fin1<<<1, 64, 0, stream>>>(sum_cp, ssq_cp, raw_gamma, raw_beta,
                                 ps_gamma, ps_beta, fu_w, fu_b, w12s_t, fb2);
    k_fu<<<6400, 256, 0, stream>>>(zcat, w12s_t, fb2, z_fu);
    k_stats<64><<<256, 256, 0, stream>>>(z_fu, sum_f, ssq_f);
    k_fin2<<<1, 64, 0, stream>>>(sum_f, ssq_f, fu_gamma, mf, rfg);
    k_out<<<1600, 256, 0, stream>>>(z_fu, mf, rfg, fu_beta, (float*)d_out);
}

// Round 5
// 436.262 us; speedup vs baseline: 2.8453x; 1.0529x over previous
//
#include <hip/hip_runtime.h>
#include <hip/hip_bf16.h>
#include <stdint.h>

#define B_   64
#define C_   3
#define J_   25
#define T_   256
#define CO_  64
#define N_   (B_*J_*T_)     // 409600 locations, loc = (b*J_+j)*T_ + t
#define SIGD 84
#define FSTR 177            // feats LDS stride (f32) — (17*lt+k)%32: 2-way banks only
#define WST  136            // w12 bf16 row stride (elements), K=128 + 8 pad

typedef short   s16x8  __attribute__((ext_vector_type(8)));
typedef __bf16  bf16x8 __attribute__((ext_vector_type(8)));
typedef float   f32x4  __attribute__((ext_vector_type(4)));
typedef float   f32x2  __attribute__((ext_vector_type(2)));

__device__ __forceinline__ unsigned short f2b(float f) {
    unsigned int u = __float_as_uint(f);
    u += 0x7fffu + ((u >> 16) & 1u);          // round-to-nearest-even
    return (unsigned short)(u >> 16);
}
__device__ __forceinline__ float b2f(unsigned int bits_lo16) {
    return __uint_as_float(bits_lo16 << 16);
}
__device__ __forceinline__ unsigned int pack2(float a, float b) {
    return (unsigned int)f2b(a) | ((unsigned int)f2b(b) << 16);
}
__device__ __forceinline__ void split2(float f, unsigned short& h, unsigned short& l) {
    h = f2b(f);
    l = f2b(f - b2f((unsigned int)h));
}

// ---------------------------------------------------------------------------
// depth-3 signature of a 3-increment path in 4 dims (verified round 1/4).
// ---------------------------------------------------------------------------
__device__ __forceinline__ void sig3(const float v0[4], const float v1[4],
                                     const float v2[4], float* __restrict__ S) {
    float* S1 = S;
    float* S2 = S + 4;
    float* S3 = S + 20;
    #pragma unroll
    for (int i = 0; i < 4; i++) S1[i] = v0[i];
    #pragma unroll
    for (int i = 0; i < 4; i++)
        #pragma unroll
        for (int j = 0; j < 4; j++) S2[i*4+j] = 0.5f * v0[i] * v0[j];
    #pragma unroll
    for (int i = 0; i < 4; i++)
        #pragma unroll
        for (int j = 0; j < 4; j++)
            #pragma unroll
            for (int k = 0; k < 4; k++)
                S3[i*16+j*4+k] = S2[i*4+j] * v0[k] * (1.f/3.f);

    #pragma unroll
    for (int s = 0; s < 2; s++) {
        const float* v = (s == 0) ? v1 : v2;
        float B2[16], v3[4];
        #pragma unroll
        for (int k = 0; k < 4; k++) v3[k] = v[k] * (1.f/3.f);
        #pragma unroll
        for (int i = 0; i < 4; i++)
            #pragma unroll
            for (int j = 0; j < 4; j++) B2[i*4+j] = 0.5f * v[i] * v[j];
        #pragma unroll
        for (int i = 0; i < 4; i++)
            #pragma unroll
            for (int j = 0; j < 4; j++)
                #pragma unroll
                for (int k = 0; k < 4; k++)
                    S3[i*16+j*4+k] += B2[i*4+j]*v3[k] + S1[i]*B2[j*4+k] + S2[i*4+j]*v[k];
        #pragma unroll
        for (int i = 0; i < 4; i++)
            #pragma unroll
            for (int j = 0; j < 4; j++) S2[i*4+j] += B2[i*4+j] + S1[i]*v[j];
        #pragma unroll
        for (int i = 0; i < 4; i++) S1[i] += v[i];
    }
}

// ---------------------------------------------------------------------------
// K0: fold signet weights through ps_w into f32 wsig_t[168][64] (k-major).
// grid=169 (k; 168=bias), block=64 (o).   (unchanged from round 4)
// ---------------------------------------------------------------------------
__global__ void k_prep(const float* __restrict__ sp_W, const float* __restrict__ sp_b,
                       const float* __restrict__ tp_W, const float* __restrict__ tp_b,
                       const float* __restrict__ ps_w, const float* __restrict__ ps_b,
                       float* __restrict__ wsig_t, float* __restrict__ cb) {
    int k = blockIdx.x;
    int o = threadIdx.x;
    if (k < SIGD) {
        float v = 0.f;
        for (int i = 0; i < 64; i++) v += sp_W[k*64+i] * ps_w[o*128+i];
        wsig_t[k*64 + o] = v;
    } else if (k < 2*SIGD) {
        int m = k - SIGD;
        float v = 0.f;
        for (int i = 0; i < 64; i++) v += tp_W[m*64+i] * ps_w[o*128+64+i];
        wsig_t[k*64 + o] = v;
    } else {
        float a = ps_b[o];
        for (int i = 0; i < 64; i++)
            a += ps_w[o*128+i]*sp_b[i] + ps_w[o*128+64+i]*tp_b[i];
        cb[o] = a;
    }
}

// ---------------------------------------------------------------------------
// K1: fused conv1x3 + signatures + packed-f32 folded matvec.
// Identical structure to round 4 except phase B uses f32x2 accumulators
// (v_pk_fma_f32). Grid: 1600 (b,j) x 4 quarters, 64 locs/block.
// ---------------------------------------------------------------------------
__global__ __launch_bounds__(256) void k_sig(const float* __restrict__ x,
                                             const int* __restrict__ nbr,
                                             const float* __restrict__ wsig_t,
                                             const float* __restrict__ cb,
                                             const float* __restrict__ conv_w,
                                             const float* __restrict__ conv_b,
                                             unsigned short* __restrict__ zcat) {
    __shared__ float feats[64*FSTR];   // 45312 B

    const int i       = threadIdx.x;
    const int quarter = blockIdx.x & 3;
    const int bj      = blockIdx.x >> 2;
    const int b       = bj / J_, j = bj % J_;
    const int loc_base = bj*T_ + quarter*64;

    if (i < 128) {
        const int lt   = i >> 1;
        const int path = i & 1;
        const int t    = quarter*64 + lt;
        float p0[4], p1[4], p2[4];
        p0[0] = 0.f; p1[0] = 0.5f; p2[0] = 1.0f;
        if (path == 0) {
            int n0 = nbr[j*3+0], n1 = nbr[j*3+1], n2 = nbr[j*3+2];
            #pragma unroll
            for (int c = 0; c < 3; c++) {
                const float* xc = x + ((size_t)(b*3+c)*J_)*T_ + t;
                p0[c+1] = xc[n0*T_];
                p1[c+1] = xc[n1*T_];
                p2[c+1] = xc[n2*T_];
            }
        } else {
            int tm = (t > 0)    ? t-1 : 0;
            int tp = (t < T_-1) ? t+1 : T_-1;
            #pragma unroll
            for (int c = 0; c < 3; c++) {
                const float* xr = x + ((size_t)(b*3+c)*J_ + j)*T_;
                p0[c+1] = xr[tm];
                p1[c+1] = xr[t];
                p2[c+1] = xr[tp];
            }
        }
        float v0[4], v1[4], v2[4];
        #pragma unroll
        for (int d = 0; d < 4; d++) { v0[d]=p0[d]; v1[d]=p1[d]-p0[d]; v2[d]=p2[d]-p1[d]; }
        float S[SIGD];
        sig3(v0, v1, v2, S);
        float* frow = feats + lt*FSTR + path*SIGD;
        #pragma unroll
        for (int m = 0; m < SIGD; m++) frow[m] = S[m];
    } else {
        const int ci  = i - 128;
        const int lt  = ci >> 1;
        const int chh = ci & 1;
        const int t   = quarter*64 + lt;
        const int loc = loc_base + lt;
        float xm[3], x0[3], xp[3];
        #pragma unroll
        for (int c = 0; c < 3; c++) {
            const float* xr = x + ((size_t)(b*3+c)*J_ + j)*T_;
            xm[c] = (t > 0)     ? xr[t-1] : 0.f;
            x0[c] = xr[t];
            xp[c] = (t < T_-1)  ? xr[t+1] : 0.f;
        }
        unsigned int packed[16];
        #pragma unroll
        for (int oo2 = 0; oo2 < 16; oo2++) {
            float r[2];
            #pragma unroll
            for (int e = 0; e < 2; e++) {
                int o = chh*32 + oo2*2 + e;
                float acc = conv_b[o];
                #pragma unroll
                for (int c = 0; c < 3; c++) {
                    const float* wr = conv_w + (o*3+c)*3;
                    acc += wr[0]*xm[c] + wr[1]*x0[c] + wr[2]*xp[c];
                }
                r[e] = fmaxf(acc, 0.f);
            }
            packed[oo2] = pack2(r[0], r[1]);
        }
        uint4* dst = (uint4*)(zcat + (size_t)loc*128 + chh*32);
        #pragma unroll
        for (int k = 0; k < 4; k++)
            dst[k] = make_uint4(packed[k*4+0], packed[k*4+1], packed[k*4+2], packed[k*4+3]);
    }
    __syncthreads();

    // ---- packed matvec: z_ps[loc][o] = relu(sum_k w[k][o]*f[loc][k]+cb) ----
    const int og = __builtin_amdgcn_readfirstlane(i >> 6);   // wave-uniform o-tile
    const int lt = i & 63;
    const int loc = loc_base + lt;
    const float* wt = wsig_t + og*16;        // + k*64
    f32x2 acc2[8];
    {
        const f32x2* cbp = (const f32x2*)(cb + og*16);
        #pragma unroll
        for (int p = 0; p < 8; p++) acc2[p] = cbp[p];
    }
    const float* frow = feats + lt*FSTR;
    #pragma unroll 4
    for (int k = 0; k < 2*SIGD; k++) {
        float f = frow[k];
        f32x2 f2 = { f, f };
        const f32x2* w2 = (const f32x2*)(wt + k*64);
        #pragma unroll
        for (int p = 0; p < 8; p++) acc2[p] += f2 * w2[p];   // v_pk_fma_f32
    }
    unsigned int pk[8];
    #pragma unroll
    for (int p = 0; p < 8; p++)
        pk[p] = pack2(fmaxf(acc2[p][0],0.f), fmaxf(acc2[p][1],0.f));
    uint4* dst = (uint4*)(zcat + (size_t)loc*128 + 64 + og*16);
    dst[0] = make_uint4(pk[0], pk[1], pk[2], pk[3]);
    dst[1] = make_uint4(pk[4], pk[5], pk[6], pk[7]);
}

// ---------------------------------------------------------------------------
// per-channel sum/ssq over [N_][NCH] bf16. (unchanged from round 4)
// ---------------------------------------------------------------------------
template<int NCH>
__global__ __launch_bounds__(256) void k_stats(const unsigned short* __restrict__ z,
                                               float* __restrict__ sum,
                                               float* __restrict__ ssq) {
    constexpr int G  = NCH/8;
    constexpr int LP = 256/G;
    const int i = threadIdx.x;
    const int g = i % G;
    const int lr = i / G;
    const int base = blockIdx.x * 1600;
    float s[8], qq[8];
    #pragma unroll
    for (int k = 0; k < 8; k++) { s[k] = 0.f; qq[k] = 0.f; }
    for (int l = lr; l < 1600; l += LP) {
        const uint4 v = *(const uint4*)(z + (size_t)(base + l)*NCH + g*8);
        unsigned int u[4] = { v.x, v.y, v.z, v.w };
        #pragma unroll
        for (int k = 0; k < 4; k++) {
            float f0 = b2f(u[k] & 0xffffu);
            float f1 = __uint_as_float(u[k] & 0xffff0000u);
            s[2*k]   += f0;  qq[2*k]   += f0*f0;
            s[2*k+1] += f1;  qq[2*k+1] += f1*f1;
        }
    }
    const int lane = i & 63, wv = i >> 6;
    for (int off = 32; off >= G; off >>= 1) {
        #pragma unroll
        for (int k = 0; k < 8; k++) {
            s[k]  += __shfl_down(s[k],  off);
            qq[k] += __shfl_down(qq[k], off);
        }
    }
    __shared__ float red[4][G][16];
    if (lane < G) {
        #pragma unroll
        for (int k = 0; k < 8; k++) { red[wv][lane][k] = s[k]; red[wv][lane][8+k] = qq[k]; }
    }
    __syncthreads();
    if (i < G*16) {
        int g2 = i >> 4, slot = i & 15;
        float v = red[0][g2][slot] + red[1][g2][slot] + red[2][g2][slot] + red[3][g2][slot];
        int ch = g2*8 + (slot & 7);
        atomicAdd((slot < 8 ? sum : ssq) + ch, v);
    }
}

// ---------------------------------------------------------------------------
// K3: finalize conv/ps BN; fold into fu weights. Emits:
//   w12h/w12l : bf16 hi/lo [64 o][WST k]  (MFMA path)
//   w12s_t    : f32 [128 k][64 o]         (scalar fallback)
//   fb2       : f32 folded bias
// ---------------------------------------------------------------------------
__global__ void k_fin1(const float* __restrict__ sum_cp, const float* __restrict__ ssq_cp,
                       const float* __restrict__ raw_g, const float* __restrict__ raw_b,
                       const float* __restrict__ ps_g,  const float* __restrict__ ps_bt,
                       const float* __restrict__ fu_w,  const float* __restrict__ fu_b,
                       unsigned short* __restrict__ w12h, unsigned short* __restrict__ w12l,
                       float* __restrict__ w12s_t, float* __restrict__ fb2) {
    __shared__ float a[128], d[128];
    int i = threadIdx.x;    // 64
    const float inv = 1.f / (float)N_;
    {
        float m = sum_cp[i]*inv, v = ssq_cp[i]*inv - m*m;
        float sc = rsqrtf(v + 1e-5f) * raw_g[i];
        a[i] = sc; d[i] = raw_b[i] - m*sc;
    }
    {
        float m = sum_cp[64+i]*inv, v = ssq_cp[64+i]*inv - m*m;
        float sc = rsqrtf(v + 1e-5f) * ps_g[i];
        a[64+i] = sc; d[64+i] = ps_bt[i] - m*sc;
    }
    __syncthreads();
    int o = i;
    float fb = fu_b[o];
    for (int k = 0; k < 128; k++) {
        float w = fu_w[o*128 + k];
        fb += w * d[k];
        float ws = w * a[k];
        w12s_t[k*64 + o] = ws;
        unsigned short h, l;
        split2(ws, h, l);
        w12h[o*WST + k] = h;
        w12l[o*WST + k] = l;
    }
    for (int k = 128; k < WST; k++) { w12h[o*WST + k] = 0; w12l[o*WST + k] = 0; }
    fb2[o] = fb;
}

// ---------------------------------------------------------------------------
// K4: fu GEMM via MFMA with in-kernel C/D-orientation probe.
// Block 256 thr, 128 locs. Grid 3200.
//   probe: A = bf16(lane&15) (row-encoded, K-permutation-proof), B = ones
//          -> D[m][n] = 32m. Ballot decides claimed vs transposed C/D map.
//   main : D[o][loc] = (Whi + Wlo) * Zt, bias+relu in epilogue (orientation-
//          aware), LDS-transpose, coalesced bf16 store.
//   fallback: scalar matvec from the staged LDS tile if neither map matches.
// ---------------------------------------------------------------------------
__global__ __launch_bounds__(256) void k_fu(const unsigned short* __restrict__ zcat,
                                            const unsigned short* __restrict__ w12h,
                                            const unsigned short* __restrict__ w12l,
                                            const float* __restrict__ w12s_t,
                                            const float* __restrict__ fb2,
                                            unsigned short* __restrict__ z_fu) {
    __shared__ __align__(16) unsigned short zt[128*WST];   // 34816 B
    const int i = threadIdx.x;
    const int loc_base = blockIdx.x * 128;

    for (int c = i; c < 2048; c += 256) {
        int row = c >> 4, k = c & 15;
        s16x8 v = *(const s16x8*)(zcat + (size_t)(loc_base + row)*128 + k*8);
        *(s16x8*)(zt + row*WST + k*8) = v;
    }
    __syncthreads();

    const int lane = i & 63, wv = i >> 6;
    const int mrow = lane & 15, q = lane >> 4;
    const f32x4 zero = {0.f, 0.f, 0.f, 0.f};

    // ---- layout probe ----
    bf16x8 ap, bp;
    #pragma unroll
    for (int jj = 0; jj < 8; jj++) { ap[jj] = (__bf16)(float)mrow; bp[jj] = (__bf16)1.0f; }
    f32x4 pv = __builtin_amdgcn_mfma_f32_16x16x32_bf16(ap, bp, zero, 0, 0, 0);
    bool cC = true, cT = true;
    #pragma unroll
    for (int r = 0; r < 4; r++) {
        cC = cC && (pv[r] == 32.f*(float)(q*4 + r));
        cT = cT && (pv[r] == 32.f*(float)mrow);
    }
    const bool okC = (__ballot(cC) == ~0ull);
    const bool okT = (!okC) && (__ballot(cT) == ~0ull);

    if (okC || okT) {
        bf16x8 ah[4], al[4];
        {
            const unsigned short* arh = w12h + (size_t)(wv*16 + mrow)*WST + q*8;
            const unsigned short* arl = w12l + (size_t)(wv*16 + mrow)*WST + q*8;
            #pragma unroll
            for (int s = 0; s < 4; s++) {
                ah[s] = __builtin_bit_cast(bf16x8, *(const s16x8*)(arh + s*32));
                al[s] = __builtin_bit_cast(bf16x8, *(const s16x8*)(arl + s*32));
            }
        }
        f32x4 accs[8];
        #pragma unroll
        for (int lt8 = 0; lt8 < 8; lt8++) {
            const unsigned short* brow = zt + (size_t)(lt8*16 + mrow)*WST + q*8;
            f32x4 acc = zero;
            #pragma unroll
            for (int s = 0; s < 4; s++) {
                bf16x8 bfrag = __builtin_bit_cast(bf16x8, *(const s16x8*)(brow + s*32));
                acc = __builtin_amdgcn_mfma_f32_16x16x32_bf16(ah[s], bfrag, acc, 0, 0, 0);
                acc = __builtin_amdgcn_mfma_f32_16x16x32_bf16(al[s], bfrag, acc, 0, 0, 0);
            }
            accs[lt8] = acc;
        }
        __syncthreads();

        unsigned short* ot = zt;       // alias as [128 loc][72 o]
        if (okC) {
            // lane holds D[o = q*4+r][loc = mrow]
            const float4 fbv = *(const float4*)(fb2 + wv*16 + q*4);
            #pragma unroll
            for (int lt8 = 0; lt8 < 8; lt8++) {
                int row = lt8*16 + mrow;
                int o   = wv*16 + q*4;
                uint2 w;
                w.x = pack2(fmaxf(accs[lt8][0]+fbv.x,0.f), fmaxf(accs[lt8][1]+fbv.y,0.f));
                w.y = pack2(fmaxf(accs[lt8][2]+fbv.z,0.f), fmaxf(accs[lt8][3]+fbv.w,0.f));
                *(uint2*)(ot + row*72 + o) = w;
            }
        } else {
            // transposed: lane holds D[o = mrow][loc = q*4+r]
            const float fb1 = fb2[wv*16 + mrow];
            #pragma unroll
            for (int lt8 = 0; lt8 < 8; lt8++) {
                #pragma unroll
                for (int r = 0; r < 4; r++) {
                    int row = lt8*16 + q*4 + r;
                    ot[row*72 + wv*16 + mrow] = f2b(fmaxf(accs[lt8][r]+fb1, 0.f));
                }
            }
        }
        __syncthreads();
        for (int c = i; c < 1024; c += 256) {
            int row = c >> 3, k = c & 7;
            s16x8 v = *(const s16x8*)(ot + row*72 + k*8);
            *(s16x8*)(z_fu + (size_t)(loc_base + row)*64 + k*8) = v;
        }
    } else {
        // ---- scalar fallback (correctness net; slow but exact) ----
        if (i < 128) {
            const unsigned short* fr = zt + i*WST;
            const int loc = loc_base + i;
            for (int og8 = 0; og8 < 8; og8++) {
                float acc[8];
                #pragma unroll
                for (int p = 0; p < 8; p++) acc[p] = fb2[og8*8 + p];
                for (int k = 0; k < 128; k++) {
                    float f = b2f(fr[k]);
                    const float* w = w12s_t + k*64 + og8*8;
                    #pragma unroll
                    for (int p = 0; p < 8; p++) acc[p] = fmaf(f, w[p], acc[p]);
                }
                #pragma unroll
                for (int p = 0; p < 8; p++)
                    z_fu[(size_t)loc*64 + og8*8 + p] = f2b(fmaxf(acc[p], 0.f));
            }
        }
    }
}

// ---------------------------------------------------------------------------
// K5: finalize fu BN stats (unchanged)
// ---------------------------------------------------------------------------
__global__ void k_fin2(const float* __restrict__ sum_f, const float* __restrict__ ssq_f,
                       const float* __restrict__ fu_g,
                       float* __restrict__ mf, float* __restrict__ rfg) {
    int o = threadIdx.x;
    const float inv = 1.f / (float)N_;
    float m = sum_f[o]*inv, v = ssq_f[o]*inv - m*m;
    mf[o] = m;
    rfg[o] = rsqrtf(v + 1e-5f) * fu_g[o];
}

// ---------------------------------------------------------------------------
// K6: apply fu BN, transpose [loc][64] -> out [b][o][j][t] f32. (unchanged)
// ---------------------------------------------------------------------------
__global__ __launch_bounds__(256) void k_out(const unsigned short* __restrict__ z_fu,
                                             const float* __restrict__ mf,
                                             const float* __restrict__ rfg,
                                             const float* __restrict__ fu_beta,
                                             float* __restrict__ out) {
    __shared__ __align__(16) unsigned short zt[256*66];
    const int i = threadIdx.x;
    const int bj = blockIdx.x;
    const int b = bj / J_, j = bj % J_;
    const int loc_base = bj * T_;

    for (int c = i; c < 2048; c += 256) {
        int row = c >> 3, k = c & 7;
        uint4 v = *(const uint4*)(z_fu + (size_t)(loc_base + row)*64 + k*8);
        unsigned int* dst = (unsigned int*)(zt + row*66 + k*8);
        dst[0] = v.x; dst[1] = v.y; dst[2] = v.z; dst[3] = v.w;
    }
    __syncthreads();

    const int t = i;
    const unsigned int* zrow = (const unsigned int*)zt + t*33;
    for (int o = 0; o < 64; o += 2) {
        unsigned int v = zrow[o >> 1];
        float f0 = b2f(v & 0xffffu);
        float f1 = __uint_as_float(v & 0xffff0000u);
        out[(((size_t)b*64 + o  )*J_ + j)*T_ + t] = (f0 - mf[o  ])*rfg[o  ] + fu_beta[o  ];
        out[(((size_t)b*64 + o+1)*J_ + j)*T_ + t] = (f1 - mf[o+1])*rfg[o+1] + fu_beta[o+1];
    }
}

// ---------------------------------------------------------------------------
extern "C" void kernel_launch(void* const* d_in, const int* in_sizes, int n_in,
                              void* d_out, int out_size, void* d_ws, size_t ws_size,
                              hipStream_t stream) {
    const float* x         = (const float*)d_in[0];
    const float* conv_w    = (const float*)d_in[1];
    const float* conv_b    = (const float*)d_in[2];
    const float* raw_gamma = (const float*)d_in[3];
    const float* raw_beta  = (const float*)d_in[4];
    const float* sp_W      = (const float*)d_in[5];
    const float* sp_b      = (const float*)d_in[6];
    const float* tp_W      = (const float*)d_in[7];
    const float* tp_b      = (const float*)d_in[8];
    const float* ps_w      = (const float*)d_in[9];
    const float* ps_b      = (const float*)d_in[10];
    const float* ps_gamma  = (const float*)d_in[11];
    const float* ps_beta   = (const float*)d_in[12];
    const float* fu_w      = (const float*)d_in[13];
    const float* fu_b      = (const float*)d_in[14];
    const float* fu_gamma  = (const float*)d_in[15];
    const float* fu_beta   = (const float*)d_in[16];
    const int*   neighbors = (const int*)d_in[17];

    char* ws = (char*)d_ws;
    unsigned short* zcat   = (unsigned short*)ws;                      // [N][128] bf16
    unsigned short* z_fu   = (unsigned short*)(ws + 104857600);        // [N][64] bf16
    size_t off = 157286400;
    float* wsig_t = (float*)(ws + off);          off += 168*64*4;      // [168][64] f32
    float* w12s_t = (float*)(ws + off);          off += 128*64*4;      // [128][64] f32
    unsigned short* w12h = (unsigned short*)(ws + off); off += 64*WST*2;
    unsigned short* w12l = (unsigned short*)(ws + off); off += 64*WST*2;
    float* f32s   = (float*)(ws + off);
    float* cb     = f32s;          // 64
    float* fb2    = f32s + 64;     // 64
    float* mf     = f32s + 128;    // 64
    float* rfg    = f32s + 192;    // 64
    float* sum_cp = f32s + 256;    // 128
    float* ssq_cp = f32s + 384;    // 128
    float* sum_f  = f32s + 512;    // 64
    float* ssq_f  = f32s + 576;    // 64

    hipMemsetAsync(sum_cp, 0, 384*sizeof(float), stream);

    k_prep<<<169, 64, 0, stream>>>(sp_W, sp_b, tp_W, tp_b, ps_w, ps_b, wsig_t, cb);
    k_sig<<<6400, 256, 0, stream>>>(x, neighbors, wsig_t, cb, conv_w, conv_b, zcat);
    k_stats<128><<<256, 256, 0, stream>>>(zcat, sum_cp, ssq_cp);
    k_fin1<<<1, 64, 0, stream>>>(sum_cp, ssq_cp, raw_gamma, raw_beta,
                                 ps_gamma, ps_beta, fu_w, fu_b,
                                 w12h, w12l, w12s_t, fb2);
    k_fu<<<3200, 256, 0, stream>>>(zcat, w12h, w12l, w12s_t, fb2, z_fu);
    k_stats<64><<<256, 256, 0, stream>>>(z_fu, sum_f, ssq_f);
    k_fin2<<<1, 64, 0, stream>>>(sum_f, ssq_f, fu_gamma, mf, rfg);
    k_out<<<1600, 256, 0, stream>>>(z_fu, mf, rfg, fu_beta, (float*)d_out);
}